// Round 6
// baseline (51.350 us; speedup 1.0000x reference)
//
#include <hip/hip_runtime.h>

// HardNMS fused kernel — LDS-free, shfl-free, branch-free inner loop.
// Round 6: halo via overlapping aligned loads (f4 + 2xf2 per plane per row),
// wave-uniform row clamp + {0,1} masks for image edges. Depth-2 prefetch.
// x: [B=16, 2, H=1024, W=1024] f32 -> out: [16, 1, 1024, 1024] f32
// xp   = relu(x[:,1] - x[:,0] - 0.1)
// xNMS = 256 * prod_{8 nbrs} relu(xp - xp_nb)   (zero-padded)
// out  = xp * maxpool3x3(xNMS)                  (xNMS >= 0 so zero-pad == -inf pad)

constexpr int Wd = 1024, Hd = 1024, Bd = 16;
constexpr int SH = 16;                 // output rows per wave strip
constexpr float EPS = 0.1f;

__device__ __forceinline__ float max3(float a, float b, float c) {
    return fmaxf(fmaxf(a, b), c);
}
__device__ __forceinline__ float reluf(float v) { return fmaxf(v, 0.f); }

// Raw prefetch buffer: center float4 + left/right float2 halos, both planes.
struct Raw { float4 a4, c4; float2 la, lc, ra, rc; };

__global__ __launch_bounds__(256, 4) void hardnms_kernel(
    const float* __restrict__ xin, float* __restrict__ out) {
    const int tid   = threadIdx.x;
    const int lane  = tid & 63;
    const int wid   = tid >> 6;
    const int xbase = blockIdx.x * 256;
    const int col0  = xbase + lane * 4;      // first owned col
    const int y0    = (blockIdx.y * 4 + wid) * SH;
    const int b     = blockIdx.z;
    const float* __restrict__ p0 = xin + (size_t)(b * 2) * Hd * Wd;
    const float* __restrict__ p1 = p0 + (size_t)Hd * Wd;

    // Per-lane halo offsets (cols) and image-x-edge masks.  At the image
    // borders we clamp the halo load in-bounds (reads garbage) and zero it.
    int   dcolL = -2; float mL = 1.f;
    int   dcolR =  4; float mR = 1.f;
    if (col0 == 0)      { dcolL = 0; mL = 0.f; }
    if (col0 == Wd - 4) { dcolR = 2; mR = 0.f; }

    // Image-y-edge masks (wave-uniform).
    const float tTop = (y0 == 0)       ? 0.f : 1.f;   // rows -2,-1
    const float tBot = (y0 == Hd - SH) ? 0.f : 1.f;   // rows SH,SH+1

    Raw RWa, RWb;

    // Issue all 6 loads for wave-uniform row gy (clamped; masked on use).
    #define ISSUE(gy, RW) do {                                              \
        const int gy_  = (gy);                                              \
        const int gyc_ = gy_ < 0 ? 0 : (gy_ > Hd - 1 ? Hd - 1 : gy_);       \
        const float* pa_ = p0 + (size_t)gyc_ * Wd;                          \
        const float* pc_ = p1 + (size_t)gyc_ * Wd;                          \
        (RW).a4 = *(const float4*)(pa_ + col0);                             \
        (RW).c4 = *(const float4*)(pc_ + col0);                             \
        (RW).la = *(const float2*)(pa_ + col0 + dcolL);                     \
        (RW).lc = *(const float2*)(pc_ + col0 + dcolL);                     \
        (RW).ra = *(const float2*)(pa_ + col0 + dcolR);                     \
        (RW).rc = *(const float2*)(pc_ + col0 + dcolR);                     \
    } while (0)

    // Build xp 8-span S[i] = xp at col0-2+i.  T is 1.0f (literal, folds)
    // for interior rows, tTop/tBot for edge rows.
    #define MAKEXP(RW, S, T) do {                                           \
        const float t_   = (T);                                             \
        const float mlt_ = mL * t_;                                         \
        const float mrt_ = mR * t_;                                         \
        S[0] = reluf((RW).lc.x - (RW).la.x - EPS) * mlt_;                   \
        S[1] = reluf((RW).lc.y - (RW).la.y - EPS) * mlt_;                   \
        S[2] = reluf((RW).c4.x - (RW).a4.x - EPS) * t_;                     \
        S[3] = reluf((RW).c4.y - (RW).a4.y - EPS) * t_;                     \
        S[4] = reluf((RW).c4.z - (RW).a4.z - EPS) * t_;                     \
        S[5] = reluf((RW).c4.w - (RW).a4.w - EPS) * t_;                     \
        S[6] = reluf((RW).rc.x - (RW).ra.x - EPS) * mrt_;                   \
        S[7] = reluf((RW).rc.y - (RW).ra.y - EPS) * mrt_;                   \
    } while (0)

    // xNMS row (6 wide, cols col0-1..col0+4) + 3-wide rowmax -> rm[4]
    #define ROWMAX_NM(A, B, C, rm) do {                                     \
        float nm_[6];                                                       \
        _Pragma("unroll")                                                   \
        for (int j = 0; j < 6; ++j) {                                       \
            const float c_ = B[j + 1];                                      \
            float p_;                                                       \
            p_  = reluf(c_ - A[j    ]);                                     \
            p_ *= reluf(c_ - A[j + 1]);                                     \
            p_ *= reluf(c_ - A[j + 2]);                                     \
            p_ *= reluf(c_ - B[j    ]);                                     \
            p_ *= reluf(c_ - B[j + 2]);                                     \
            p_ *= reluf(c_ - C[j    ]);                                     \
            p_ *= reluf(c_ - C[j + 1]);                                     \
            p_ *= reluf(c_ - C[j + 2]);                                     \
            nm_[j] = p_;                                                    \
        }                                                                   \
        rm[0] = max3(nm_[0], nm_[1], nm_[2]);                               \
        rm[1] = max3(nm_[1], nm_[2], nm_[3]);                               \
        rm[2] = max3(nm_[2], nm_[3], nm_[4]);                               \
        rm[3] = max3(nm_[3], nm_[4], nm_[5]);                               \
    } while (0)

    #define EMIT(CTR, ra, rb, rc) do {                                      \
        float4 o_;                                                          \
        o_.x = CTR[2] * 256.f * max3(ra[0], rb[0], rc[0]);                  \
        o_.y = CTR[3] * 256.f * max3(ra[1], rb[1], rc[1]);                  \
        o_.z = CTR[4] * 256.f * max3(ra[2], rb[2], rc[2]);                  \
        o_.w = CTR[5] * 256.f * max3(ra[3], rb[3], rc[3]);                  \
        *(float4*)po = o_;                                                  \
        po += Wd;                                                           \
    } while (0)

    float R0[8], R1[8], R2[8], R3[8];
    float rm0[4], rm1[4], rm2[4], rm3[4];

    // Prologue: row r's raw lives in RW[r&1]; its xp span in R[r&3]
    // (r = gy - y0 in [-2, SH+1]).  Depth-2 rotation: consume r, issue r+2.
    ISSUE(y0 - 2, RWa);                   // row -2
    ISSUE(y0 - 1, RWb);                   // row -1
    MAKEXP(RWa, R2, tTop);                // row -2
    ISSUE(y0 + 0, RWa);                   // row  0
    MAKEXP(RWb, R3, tTop);                // row -1
    ISSUE(y0 + 1, RWb);                   // row  1
    MAKEXP(RWa, R0, 1.0f);                // row  0
    ISSUE(y0 + 2, RWa);                   // row  2
    ROWMAX_NM(R2, R3, R0, rm3);           // nm row -1
    MAKEXP(RWb, R1, 1.0f);                // row  1
    ISSUE(y0 + 3, RWb);                   // row  3
    ROWMAX_NM(R3, R0, R1, rm0);           // nm row 0

    float* po = out + (size_t)b * Hd * Wd + (size_t)y0 * Wd + col0;

    // Steady state: step k consumes raw row k+2 (RW[(k+2)&1]), issues row
    // k+4 into the same buffer (guard k <= SH-3 so last issued row = SH+1),
    // computes nm row k+1, emits output row k.
    #pragma unroll
    for (int k4 = 0; k4 < SH / 4; ++k4) {
        const int kb = k4 * 4;
        // k = kb+0 : raw row kb+2 (even -> RWa)
        MAKEXP(RWa, R2, (kb + 2 >= SH) ? tBot : 1.0f);
        if (kb + 0 <= SH - 3) ISSUE(y0 + kb + 4, RWa);
        ROWMAX_NM(R0, R1, R2, rm1);
        EMIT(R0, rm3, rm0, rm1);
        // k = kb+1 : raw row kb+3 (RWb)
        MAKEXP(RWb, R3, (kb + 3 >= SH) ? tBot : 1.0f);
        if (kb + 1 <= SH - 3) ISSUE(y0 + kb + 5, RWb);
        ROWMAX_NM(R1, R2, R3, rm2);
        EMIT(R1, rm0, rm1, rm2);
        // k = kb+2 : raw row kb+4 (RWa)
        MAKEXP(RWa, R0, (kb + 4 >= SH) ? tBot : 1.0f);
        if (kb + 2 <= SH - 3) ISSUE(y0 + kb + 6, RWa);
        ROWMAX_NM(R2, R3, R0, rm3);
        EMIT(R2, rm1, rm2, rm3);
        // k = kb+3 : raw row kb+5 (RWb)
        MAKEXP(RWb, R1, (kb + 5 >= SH) ? tBot : 1.0f);
        if (kb + 3 <= SH - 3) ISSUE(y0 + kb + 7, RWb);
        ROWMAX_NM(R3, R0, R1, rm0);
        EMIT(R3, rm2, rm3, rm0);
    }

    #undef ISSUE
    #undef MAKEXP
    #undef ROWMAX_NM
    #undef EMIT
}

extern "C" void kernel_launch(void* const* d_in, const int* in_sizes, int n_in,
                              void* d_out, int out_size, void* d_ws, size_t ws_size,
                              hipStream_t stream) {
    const float* xin = (const float*)d_in[0];
    float* out = (float*)d_out;
    dim3 grid(Wd / 256, Hd / (4 * SH), Bd);   // (4, 16, 16)
    hardnms_kernel<<<grid, dim3(256), 0, stream>>>(xin, out);
}